// Round 1
// baseline (547.393 us; speedup 1.0000x reference)
//
#include <hip/hip_runtime.h>
#include <math.h>

namespace {
constexpr int kB = 16, kH = 64, kW = 64, kC = 512;
constexpr int kR = 256, kN = 64, kPH = 7, kPW = 7;
constexpr int kC4 = kC / 4;              // 128 float4 channel groups
constexpr float kIouThr = 0.4f;
constexpr size_t kPooledElems = (size_t)kB * kN * kPH * kPW * kC; // 25,690,112
}

__device__ __forceinline__ float4 max4(float4 a, float4 b) {
    return make_float4(fmaxf(a.x, b.x), fmaxf(a.y, b.y),
                       fmaxf(a.z, b.z), fmaxf(a.w, b.w));
}

// One wave (64 lanes) per batch. Greedy NMS in index order via shfl+ballot,
// then rank/select 64 regions, clip boxes, write roi_clipped (as float) to
// the tail of d_out.
__global__ __launch_bounds__(64) void nms_clip_kernel(
        const float* __restrict__ roi, float* __restrict__ out_roi) {
    const int b = blockIdx.x;
    const int lane = threadIdx.x;                 // 0..63
    const float* r = roi + (size_t)b * kR * 4;

    // lane holds boxes s*64+lane for s in 0..3
    float x1[4], y1[4], x2[4], y2[4], ar[4];
    bool keep[4];
#pragma unroll
    for (int s = 0; s < 4; ++s) {
        const int i = s * 64 + lane;
        const float x = r[i * 4 + 0], y = r[i * 4 + 1];
        const float w = r[i * 4 + 2], h = r[i * 4 + 3];
        x1[s] = x; y1[s] = y; x2[s] = x + w; y2[s] = y + h;
        ar[s] = (y2[s] - y1[s]) * (x2[s] - x1[s]);
        keep[s] = false;
    }

    // greedy scan: keep[i] = !any(keep[j] && iou(i,j) > thr)
    for (int i = 0; i < kR; ++i) {
        const int src = i & 63;
        const int slot = i >> 6;                  // wave-uniform
        const float bx1 = __shfl(x1[slot], src);
        const float by1 = __shfl(y1[slot], src);
        const float bx2 = __shfl(x2[slot], src);
        const float by2 = __shfl(y2[slot], src);
        const float bar = __shfl(ar[slot], src);
        bool hit = false;
#pragma unroll
        for (int s = 0; s < 4; ++s) {
            if (keep[s]) {
                float ih = fmaxf(fminf(by2, y2[s]) - fmaxf(by1, y1[s]), 0.0f);
                float iw = fmaxf(fminf(bx2, x2[s]) - fmaxf(bx1, x1[s]), 0.0f);
                const float inter = ih * iw;
                const float uni = bar + ar[s] - inter;
                const float iou = (uni > 0.0f) ? (inter / uni) : 0.0f;
                hit = hit || (iou > kIouThr);
            }
        }
        const unsigned long long bal = __ballot(hit);
        if (lane == src && bal == 0ull) keep[slot] = true;
    }

    // ranks via ballots
    unsigned long long bals[4];
#pragma unroll
    for (int s = 0; s < 4; ++s) bals[s] = __ballot(keep[s]);
    int base[4];
    base[0] = 0;
    base[1] = __popcll(bals[0]);
    base[2] = base[1] + __popcll(bals[1]);
    base[3] = base[2] + __popcll(bals[2]);
    const unsigned long long below =
        (lane == 0) ? 0ull : (~0ull >> (64 - lane));

    __shared__ int idx[kN];
    if (lane < kN) idx[lane] = kR - kN + lane;    // fill = 192+k
    __syncthreads();
#pragma unroll
    for (int s = 0; s < 4; ++s) {
        if (keep[s]) {
            const int rank = base[s] + __popcll(bals[s] & below);
            if (rank < kN) idx[rank] = s * 64 + lane;
        }
    }
    __syncthreads();

    if (lane < kN) {
        const int i = idx[lane];
        const float x = r[i * 4 + 0], y = r[i * 4 + 1];
        const float w = r[i * 4 + 2], h = r[i * 4 + 3];
        int x_min = (int)fmaxf(0.0f, x);
        int y_min = (int)fmaxf(0.0f, y);
        int x_max = (int)fminf((float)kW, x + w);
        int y_max = (int)fminf((float)kH, y + h);
        // _fix_axis(x, ps=7, fs=64); >>1 == Python floor-div by 2
        {
            const int pad = kPW - (x_max - x_min);
            const bool fmn = x_min < (pad >> 1);
            const bool fmx = (kW - x_max) < ((1 + pad) >> 1);
            const bool sym = (pad > 0) && !(fmn || fmx);
            int omin = sym ? (x_min - (pad >> 1)) : x_min;
            int omax = sym ? (x_max + ((1 + pad) >> 1)) : x_max;
            if ((pad > 0) && fmn) { omin = 0; omax = kPW; }
            if ((pad > 0) && fmx) { omin = kW - kPW; omax = kW; }
            x_min = omin; x_max = omax;
        }
        {
            const int pad = kPH - (y_max - y_min);
            const bool fmn = y_min < (pad >> 1);
            const bool fmx = (kH - y_max) < ((1 + pad) >> 1);
            const bool sym = (pad > 0) && !(fmn || fmx);
            int omin = sym ? (y_min - (pad >> 1)) : y_min;
            int omax = sym ? (y_max + ((1 + pad) >> 1)) : y_max;
            if ((pad > 0) && fmn) { omin = 0; omax = kPH; }
            if ((pad > 0) && fmx) { omin = kH - kPH; omax = kH; }
            y_min = omin; y_max = omax;
        }
        float4 rf;
        rf.x = (float)x_min; rf.y = (float)y_min;
        rf.z = (float)(x_max - x_min); rf.w = (float)(y_max - y_min);
        ((float4*)out_roi)[b * kN + lane] = rf;
    }
}

// One block per (b, region). 128 threads, each owns one float4 channel group.
// Reads roi_clipped (exact small ints stored as float) from d_out tail.
__global__ __launch_bounds__(128) void pool_kernel(
        const float4* __restrict__ fm4, const float4* __restrict__ rcf,
        float4* __restrict__ out4) {
    const int rid = blockIdx.x;                   // b*64 + n
    const int b = rid >> 6;
    const int t = threadIdx.x;                    // channel group
    const float4 rf = rcf[rid];
    const int x = (int)rf.x, y = (int)rf.y;
    const int w = (int)rf.z, h = (int)rf.w;       // w,h >= 7 guaranteed

    const float4* fm = fm4 + (size_t)b * kH * kW * kC4;
    float4* out = out4 + (size_t)rid * (kPH * kPW) * kC4;

    const float NI = -__builtin_inff();
    const float4 ninf = make_float4(NI, NI, NI, NI);

    // rows y..y+5: 6x6 block copy + column strip (cols x+6..x+w-1)
#pragma unroll
    for (int p = 0; p < 6; ++p) {
        const float4* row = fm + (size_t)(y + p) * kW * kC4 + t;
#pragma unroll
        for (int q = 0; q < 6; ++q) {
            out[(p * 7 + q) * kC4 + t] = row[(size_t)(x + q) * kC4];
        }
        float4 m = ninf;
        for (int j = x + 6; j < x + w; ++j) {
            m = max4(m, row[(size_t)j * kC4]);
        }
        out[(p * 7 + 6) * kC4 + t] = m;
    }

    // rows y+6..y+h-1: 6 row strips (cols x..x+5) + corner
    float4 ms[6];
#pragma unroll
    for (int q = 0; q < 6; ++q) ms[q] = ninf;
    float4 corner = ninf;
    for (int i = y + 6; i < y + h; ++i) {
        const float4* row = fm + (size_t)i * kW * kC4 + t;
#pragma unroll
        for (int q = 0; q < 6; ++q) {
            ms[q] = max4(ms[q], row[(size_t)(x + q) * kC4]);
        }
        for (int j = x + 6; j < x + w; ++j) {
            corner = max4(corner, row[(size_t)j * kC4]);
        }
    }
#pragma unroll
    for (int q = 0; q < 6; ++q) out[(6 * 7 + q) * kC4 + t] = ms[q];
    out[48 * kC4 + t] = corner;
}

extern "C" void kernel_launch(void* const* d_in, const int* in_sizes, int n_in,
                              void* d_out, int out_size, void* d_ws, size_t ws_size,
                              hipStream_t stream) {
    (void)in_sizes; (void)n_in; (void)d_ws; (void)ws_size; (void)out_size;
    const float* features = (const float*)d_in[0];
    const float* roi = (const float*)d_in[1];
    float* out = (float*)d_out;
    float* out_roi = out + kPooledElems;          // roi_clipped tail

    nms_clip_kernel<<<kB, 64, 0, stream>>>(roi, out_roi);
    pool_kernel<<<kB * kN, 128, 0, stream>>>(
        (const float4*)features, (const float4*)out_roi, (float4*)out);
}

// Round 2
// 346.477 us; speedup vs baseline: 1.5799x; 1.5799x over previous
//
#include <hip/hip_runtime.h>
#include <math.h>

namespace {
constexpr int kB = 16, kH = 64, kW = 64, kC = 512;
constexpr int kR = 256, kN = 64, kPH = 7, kPW = 7;
constexpr int kC4 = kC / 4;              // 128 float4 channel groups
constexpr float kIouThr = 0.4f;
constexpr size_t kPooledElems = (size_t)kB * kN * kPH * kPW * kC; // 25,690,112
}

__device__ __forceinline__ float4 max4(float4 a, float4 b) {
    return make_float4(fmaxf(a.x, b.x), fmaxf(a.y, b.y),
                       fmaxf(a.z, b.z), fmaxf(a.w, b.w));
}

// One block (256 threads) per batch. Bitmask NMS:
//   phase 1: thread i computes 256-bit row mask M[i] (iou(i,j) > thr), parallel.
//   phase 2: thread 0 does the greedy scan with pure register ops + LDS prefetch.
//   phase 3: parallel rank/select, then clip, write roi_clipped to d_out tail.
__global__ __launch_bounds__(256) void nms_clip_kernel(
        const float* __restrict__ roi, float* __restrict__ out_roi) {
    const int b = blockIdx.x;
    const int tid = threadIdx.x;                  // 0..255 = box index
    const float* r = roi + (size_t)b * kR * 4;

    __shared__ float4 box[kR];                    // x1,y1,x2,y2
    __shared__ float area[kR];
    __shared__ unsigned long long M[kR][4];
    __shared__ unsigned long long kw[4];
    __shared__ int idx[kN];

    if (tid < kN) idx[tid] = kR - kN + tid;       // fill = 192+k

    const float4 rr = ((const float4*)r)[tid];    // x,y,w,h
    const float x1 = rr.x, y1 = rr.y, x2 = rr.x + rr.z, y2 = rr.y + rr.w;
    box[tid] = make_float4(x1, y1, x2, y2);
    area[tid] = (y2 - y1) * (x2 - x1);
    __syncthreads();

    // phase 1: row masks
    {
        unsigned long long m0 = 0, m1 = 0, m2 = 0, m3 = 0;
        const float ai = area[tid];
        for (int j = 0; j < kR; ++j) {
            const float4 bj = box[j];             // LDS broadcast (uniform j)
            const float ih = fmaxf(fminf(y2, bj.w) - fmaxf(y1, bj.y), 0.0f);
            const float iw = fmaxf(fminf(x2, bj.z) - fmaxf(x1, bj.x), 0.0f);
            const float inter = ih * iw;
            const float uni = ai + area[j] - inter;
            const float iou = (uni > 0.0f) ? (inter / uni) : 0.0f;
            if (iou > kIouThr) {
                const unsigned long long bit = 1ull << (j & 63);
                if ((j >> 6) == 0) m0 |= bit;
                else if ((j >> 6) == 1) m1 |= bit;
                else if ((j >> 6) == 2) m2 |= bit;
                else m3 |= bit;
            }
        }
        M[tid][0] = m0; M[tid][1] = m1; M[tid][2] = m2; M[tid][3] = m3;
    }
    __syncthreads();

    // phase 2: greedy scan (sequential, single thread, register-only chain)
    if (tid == 0) {
        unsigned long long s0 = 0, s1 = 0, s2 = 0, s3 = 0;
        unsigned long long k0 = 0, k1 = 0, k2 = 0, k3 = 0;
        unsigned long long n0 = M[0][0], n1 = M[0][1], n2 = M[0][2], n3 = M[0][3];
#pragma unroll
        for (int wi = 0; wi < 4; ++wi) {
            for (int bi = 0; bi < 64; ++bi) {
                const unsigned long long m0 = n0, m1 = n1, m2 = n2, m3 = n3;
                const int ip = (wi * 64 + bi + 1) & 255;   // prefetch next row
                n0 = M[ip][0]; n1 = M[ip][1]; n2 = M[ip][2]; n3 = M[ip][3];
                const unsigned long long sw =
                    (wi == 0) ? s0 : (wi == 1) ? s1 : (wi == 2) ? s2 : s3;
                if (!((sw >> bi) & 1ull)) {
                    const unsigned long long bit = 1ull << bi;
                    if (wi == 0) k0 |= bit;
                    else if (wi == 1) k1 |= bit;
                    else if (wi == 2) k2 |= bit;
                    else k3 |= bit;
                    s0 |= m0; s1 |= m1; s2 |= m2; s3 |= m3;
                }
            }
        }
        kw[0] = k0; kw[1] = k1; kw[2] = k2; kw[3] = k3;
    }
    __syncthreads();

    // phase 3: rank + scatter
    {
        const int wi = tid >> 6, bi = tid & 63;
        const unsigned long long kwv = kw[wi];
        if ((kwv >> bi) & 1ull) {
            int rank = 0;
            for (int w2 = 0; w2 < wi; ++w2) rank += __popcll(kw[w2]);
            const unsigned long long below =
                (bi == 0) ? 0ull : (~0ull >> (64 - bi));
            rank += __popcll(kwv & below);
            if (rank < kN) idx[rank] = tid;
        }
    }
    __syncthreads();

    if (tid < kN) {
        const int i = idx[tid];
        const float x = r[i * 4 + 0], y = r[i * 4 + 1];
        const float w = r[i * 4 + 2], h = r[i * 4 + 3];
        int x_min = (int)fmaxf(0.0f, x);
        int y_min = (int)fmaxf(0.0f, y);
        int x_max = (int)fminf((float)kW, x + w);
        int y_max = (int)fminf((float)kH, y + h);
        // _fix_axis(ps=7, fs=64); >>1 matches Python floor-div by 2
        {
            const int pad = kPW - (x_max - x_min);
            const bool fmn = x_min < (pad >> 1);
            const bool fmx = (kW - x_max) < ((1 + pad) >> 1);
            const bool sym = (pad > 0) && !(fmn || fmx);
            int omin = sym ? (x_min - (pad >> 1)) : x_min;
            int omax = sym ? (x_max + ((1 + pad) >> 1)) : x_max;
            if ((pad > 0) && fmn) { omin = 0; omax = kPW; }
            if ((pad > 0) && fmx) { omin = kW - kPW; omax = kW; }
            x_min = omin; x_max = omax;
        }
        {
            const int pad = kPH - (y_max - y_min);
            const bool fmn = y_min < (pad >> 1);
            const bool fmx = (kH - y_max) < ((1 + pad) >> 1);
            const bool sym = (pad > 0) && !(fmn || fmx);
            int omin = sym ? (y_min - (pad >> 1)) : y_min;
            int omax = sym ? (y_max + ((1 + pad) >> 1)) : y_max;
            if ((pad > 0) && fmn) { omin = 0; omax = kPH; }
            if ((pad > 0) && fmx) { omin = kH - kPH; omax = kH; }
            y_min = omin; y_max = omax;
        }
        float4 rf;
        rf.x = (float)x_min; rf.y = (float)y_min;
        rf.z = (float)(x_max - x_min); rf.w = (float)(y_max - y_min);
        ((float4*)out_roi)[b * kN + tid] = rf;
    }
}

// One block per (b, region); 512 threads = 4 sections x 128 channel groups.
// Sections split the 6 top rows and the (h-6)-row bottom scan; sections 1-3
// write 7 float4 partials to LDS, section 0 reduces and writes output row 6.
__global__ __launch_bounds__(512) void pool_kernel(
        const float4* __restrict__ fm4, const float4* __restrict__ rcf,
        float4* __restrict__ out4) {
    const int rid = blockIdx.x;                   // b*64 + n
    const int b = rid >> 6;
    const int tid = threadIdx.x;
    const int s = tid >> 7;                       // section 0..3
    const int t = tid & 127;                      // channel group
    const float4 rf = rcf[rid];
    const int x = (int)rf.x, y = (int)rf.y;
    const int w = (int)rf.z, h = (int)rf.w;       // w,h >= 7 guaranteed

    const float4* fm = fm4 + (size_t)b * kH * kW * kC4;
    float4* out = out4 + (size_t)rid * (kPH * kPW) * kC4;

    const float NI = -__builtin_inff();
    const float4 ninf = make_float4(NI, NI, NI, NI);

    // top rows p=0..5: sections take p = s, s+4
    for (int p = s; p < 6; p += 4) {
        const float4* row = fm + (size_t)(y + p) * kW * kC4 + t;
#pragma unroll
        for (int q = 0; q < 6; ++q) {
            out[(p * 7 + q) * kC4 + t] = row[(size_t)(x + q) * kC4];
        }
        float4 m = ninf;
        for (int j = x + 6; j < x + w; ++j) {
            m = max4(m, row[(size_t)j * kC4]);
        }
        out[(p * 7 + 6) * kC4 + t] = m;
    }

    // bottom rows i in [y+6, y+h): strided by section
    float4 pm[7];
#pragma unroll
    for (int o = 0; o < 7; ++o) pm[o] = ninf;
    for (int i = y + 6 + s; i < y + h; i += 4) {
        const float4* row = fm + (size_t)i * kW * kC4 + t;
#pragma unroll
        for (int q = 0; q < 6; ++q) {
            pm[q] = max4(pm[q], row[(size_t)(x + q) * kC4]);
        }
        float4 c = pm[6];
        for (int j = x + 6; j < x + w; ++j) {
            c = max4(c, row[(size_t)j * kC4]);
        }
        pm[6] = c;
    }

    __shared__ float4 red[3][7][128];             // 43008 B -> 3 blocks/CU
    if (s > 0) {
#pragma unroll
        for (int o = 0; o < 7; ++o) red[s - 1][o][t] = pm[o];
    }
    __syncthreads();
    if (s == 0) {
#pragma unroll
        for (int o = 0; o < 7; ++o) {
            float4 v = pm[o];
            v = max4(v, red[0][o][t]);
            v = max4(v, red[1][o][t]);
            v = max4(v, red[2][o][t]);
            out[(42 + o) * kC4 + t] = v;
        }
    }
}

extern "C" void kernel_launch(void* const* d_in, const int* in_sizes, int n_in,
                              void* d_out, int out_size, void* d_ws, size_t ws_size,
                              hipStream_t stream) {
    (void)in_sizes; (void)n_in; (void)d_ws; (void)ws_size; (void)out_size;
    const float* features = (const float*)d_in[0];
    const float* roi = (const float*)d_in[1];
    float* out = (float*)d_out;
    float* out_roi = out + kPooledElems;          // roi_clipped tail

    nms_clip_kernel<<<kB, 256, 0, stream>>>(roi, out_roi);
    pool_kernel<<<kB * kN, 512, 0, stream>>>(
        (const float4*)features, (const float4*)out_roi, (float4*)out);
}